// Round 9
// baseline (700.391 us; speedup 1.0000x reference)
//
#include <hip/hip_runtime.h>
#include <hip/hip_bf16.h>
#include <cmath>

typedef __bf16 bf16_t;
typedef __bf16 bf16x8 __attribute__((ext_vector_type(8)));
typedef short  s16x8  __attribute__((ext_vector_type(8)));
typedef float  f32x4  __attribute__((ext_vector_type(4)));

static constexpr int Bn  = 2;
static constexpr int Sn  = 2048;
static constexpr int Dn  = 1024;
static constexpr int Hn  = 16;
static constexpr int In  = 3752;
static constexpr int Mn  = Bn * Sn;   // 4096 rows
static constexpr int Ipad = 3840;     // In padded to 128

// async 16B global->LDS copy: lane i's 16B lands at ldsbase + i*16 (m97/m104).
__device__ __forceinline__ void cp16(const bf16_t* g, bf16_t* l) {
  __builtin_amdgcn_global_load_lds(
      (const __attribute__((address_space(1))) unsigned int*)g,
      (__attribute__((address_space(3))) unsigned int*)l, 16, 0, 0);
}

// XCD-aware bijective block swizzle (measured neutral, harmless; kept for k_gemm64)
__device__ __forceinline__ void xcd_map(int bid, int nM, int nN, int& m, int& n) {
  const int q = (nM * nN) >> 3;
  const int L = (bid & 7) * q + (bid >> 3);
  const int bandw = nN << 3;
  const int band = L / bandw;
  const int rem  = L - band * bandw;
  n = rem >> 3;
  m = (band << 3) + (rem & 7);
}

// ---------------------------------------------------------------- batched transpose + cast
struct TransJob  { const float* src; bf16_t* dst; int R, C, bx, start; };
struct TransJobs { TransJob j[7]; };

__global__ __launch_bounds__(256) void k_transpose_all(TransJobs jobs) {
  const int bid = blockIdx.x;
  int jj = 0;
#pragma unroll
  for (int t = 1; t < 7; ++t)
    if (bid >= jobs.j[t].start) jj = t;
  const TransJob jb = jobs.j[jj];
  const int local = bid - jb.start;
  const int r0 = (local / jb.bx) * 32, c0 = (local % jb.bx) * 32;
  __shared__ float tile[32][33];
  const int tx = threadIdx.x & 31, ty = threadIdx.x >> 5;
#pragma unroll
  for (int e = 0; e < 4; ++e) {
    int r = r0 + ty + e * 8, c = c0 + tx;
    if (r < jb.R && c < jb.C) tile[ty + e * 8][tx] = jb.src[(size_t)r * jb.C + c];
  }
  __syncthreads();
#pragma unroll
  for (int e = 0; e < 4; ++e) {
    int c = c0 + ty + e * 8, r = r0 + tx;
    if (r < jb.R && c < jb.C) jb.dst[(size_t)c * jb.R + r] = (bf16_t)tile[tx][ty + e * 8];
  }
}

// ---------------------------------------------------------------- rmsnorm (f32 -> bf16)
__global__ __launch_bounds__(256) void k_rmsnorm(const float* __restrict__ in,
                                                 const float* __restrict__ w,
                                                 bf16_t* __restrict__ out) {
  const int row = blockIdx.x;
  const int tid = threadIdx.x;
  const float* ip = in + (size_t)row * Dn;
  float v[4];
  float ss = 0.f;
#pragma unroll
  for (int e = 0; e < 4; ++e) {
    v[e] = ip[tid + e * 256];
    ss += v[e] * v[e];
  }
  for (int off = 32; off > 0; off >>= 1) ss += __shfl_down(ss, off);
  __shared__ float red[4];
  if ((tid & 63) == 0) red[tid >> 6] = ss;
  __syncthreads();
  float tot = red[0] + red[1] + red[2] + red[3];
  float sc = rsqrtf(tot * (1.0f / Dn) + 1e-6f);
  bf16_t* op = out + (size_t)row * Dn;
#pragma unroll
  for (int e = 0; e < 4; ++e) {
    int idx = tid + e * 256;
    op[idx] = (bf16_t)(w[idx] * v[e] * sc);
  }
}

// ---------------------------------------------------------------- 256x128 pipelined GEMM
// 4 waves (2M x 2N), wave tile 128x64: 12 ds_read_b128 feed 32 MFMA per
// K-step (gateup's proven read:MFMA balance; the old 64x64 tile at 8:16 was
// read-bound). Verified depth-2 / counted-vmcnt(6) schedule; LDS 72 KB ->
// 2 blocks/CU; VGPR ~210 -> 2 waves/SIMD.
// MODE 0: qkv epilogue (3-way bias, bf16 out ld 3072), K = Dn.
// MODE 1: down split-K partial (f32 out ld Dn at part + z*Mn*Dn), K-slice
//         of Ipad/2 selected by blockIdx.z.
template <int MODE>
__global__ __launch_bounds__(256, 2) void k_gemm256x128(
    const bf16_t* __restrict__ A, const bf16_t* __restrict__ Bt,
    const float* __restrict__ b0, const float* __restrict__ b1,
    const float* __restrict__ b2, void* __restrict__ outv,
    int lda, int ldb) {
  __shared__ bf16_t As[3][256 * 32];
  __shared__ bf16_t Bs[3][128 * 32];
  const int m0 = blockIdx.x * 256, n0 = blockIdx.y * 128;
  const int kbase = (MODE == 1) ? (int)blockIdx.z * (Ipad / 2) : 0;
  const int tid = threadIdx.x;
  const int lane = tid & 63, w = tid >> 6;
  const int wm = w >> 1, wn = w & 1;      // 2 m-waves x 2 n-waves
  const int l15 = lane & 15, quad = lane >> 4;
  const int sw2 = (l15 >> 1) & 3;

  // staging: A covers 4 slabs of 64 rows, B covers 2 slabs
  int arow[4], achk[4], aslab[4];
#pragma unroll
  for (int c = 0; c < 4; ++c) {
    const int r = (tid >> 2) + 64 * c;
    arow[c]  = r;
    achk[c]  = ((tid & 3) ^ ((r >> 1) & 3)) * 8;
    aslab[c] = c * 2048 + w * 512;
  }

  f32x4 acc[8][4];
  const f32x4 z4 = {0.f, 0.f, 0.f, 0.f};
#pragma unroll
  for (int i = 0; i < 8; ++i)
#pragma unroll
    for (int j = 0; j < 4; ++j) acc[i][j] = z4;

  const int NT = (MODE == 1) ? (Ipad / 2) / 32 : Dn / 32;

  auto stage = [&](int t) {
    const int bi = t - (t / 3) * 3;
    const int k0 = kbase + t * 32;
#pragma unroll
    for (int c = 0; c < 4; ++c)
      cp16(A + (size_t)(m0 + arow[c]) * lda + k0 + achk[c], &As[bi][aslab[c]]);
#pragma unroll
    for (int c = 0; c < 2; ++c)
      cp16(Bt + (size_t)(n0 + arow[c]) * ldb + k0 + achk[c], &Bs[bi][aslab[c]]);
  };

  stage(0);
  stage(1);
  asm volatile("s_waitcnt vmcnt(6)" ::: "memory");
  asm volatile("s_barrier" ::: "memory");

  for (int t = 0; t < NT; ++t) {
    const int bi = t - (t / 3) * 3;
    if (t + 2 < NT) stage(t + 2);

    bf16x8 af[8], bfr[4];
#pragma unroll
    for (int i = 0; i < 8; ++i) {
      const int r2 = wm * 128 + i * 16 + l15;
      af[i] = *(const bf16x8*)(&As[bi][r2 * 32 + ((quad ^ sw2) * 8)]);
    }
#pragma unroll
    for (int j = 0; j < 4; ++j) {
      const int r2 = wn * 64 + j * 16 + l15;
      bfr[j] = *(const bf16x8*)(&Bs[bi][r2 * 32 + ((quad ^ sw2) * 8)]);
    }
    __builtin_amdgcn_s_setprio(1);
#pragma unroll
    for (int i = 0; i < 8; ++i)
#pragma unroll
      for (int j = 0; j < 4; ++j)
        acc[i][j] = __builtin_amdgcn_mfma_f32_16x16x32_bf16(af[i], bfr[j], acc[i][j], 0, 0, 0);
    __builtin_amdgcn_s_setprio(0);

    if (t + 2 < NT) asm volatile("s_waitcnt vmcnt(6)" ::: "memory");
    else            asm volatile("s_waitcnt vmcnt(0)" ::: "memory");
    asm volatile("s_barrier" ::: "memory");
  }

#pragma unroll
  for (int i = 0; i < 8; ++i)
#pragma unroll
    for (int j = 0; j < 4; ++j) {
      const int col = n0 + wn * 64 + j * 16 + l15;
      if (MODE == 0) {
        const int sel = col >> 10;
        const float bval = (sel == 0) ? b0[col] : (sel == 1) ? b1[col - 1024] : b2[col - 2048];
        bf16_t* out = (bf16_t*)outv;
#pragma unroll
        for (int r = 0; r < 4; ++r) {
          const int row = m0 + wm * 128 + i * 16 + quad * 4 + r;
          out[(size_t)row * 3072 + col] = (bf16_t)(acc[i][j][r] + bval);
        }
      } else {
        float* outp = (float*)outv + (size_t)blockIdx.z * Mn * Dn;
#pragma unroll
        for (int r = 0; r < 4; ++r) {
          const int row = m0 + wm * 128 + i * 16 + quad * 4 + r;
          outp[(size_t)row * Dn + col] = acc[i][j][r];
        }
      }
    }
}

// out = a + b + c (f32, vectorized) — split-K combine with residual
__global__ __launch_bounds__(256) void k_combine(
    const float* __restrict__ a, const float* __restrict__ b,
    const float* __restrict__ c, float* __restrict__ out) {
  const size_t i = ((size_t)blockIdx.x * 256 + threadIdx.x) * 4;
  const f32x4 va = *(const f32x4*)(a + i);
  const f32x4 vb = *(const f32x4*)(b + i);
  const f32x4 vc = *(const f32x4*)(c + i);
  f32x4 vo;
#pragma unroll
  for (int e = 0; e < 4; ++e) vo[e] = va[e] + vb[e] + vc[e];
  *(f32x4*)(out + i) = vo;
}

// ---------------------------------------------------------------- fused gate/up, 128x128 pipelined
// (verified R3) 256 threads, BK=32, 3 LDS buffers, depth-2, counted vmcnt(6).
__global__ __launch_bounds__(256, 2) void k_gateup(
    const bf16_t* __restrict__ A, const bf16_t* __restrict__ Bg,
    const bf16_t* __restrict__ Bu, bf16_t* __restrict__ out) {
  __shared__ bf16_t As[3][128 * 32];
  __shared__ bf16_t Gs[3][128 * 32];
  __shared__ bf16_t Us[3][128 * 32];
  const int m0 = blockIdx.x * 128, n0 = blockIdx.y * 128;
  const int tid = threadIdx.x;
  const int lane = tid & 63, w = tid >> 6;
  const int wm = w >> 1, wn = w & 1;
  const int l15 = lane & 15, quad = lane >> 4;
  const int sw2 = (l15 >> 1) & 3;

  int arow[2], brow[2], chk[2], slab[2];
#pragma unroll
  for (int c = 0; c < 2; ++c) {
    const int r = (tid >> 2) + 64 * c;
    arow[c] = m0 + r;
    brow[c] = min(n0 + r, In - 1);
    chk[c]  = ((tid & 3) ^ ((r >> 1) & 3)) * 8;
    slab[c] = c * 2048 + w * 512;
  }

  f32x4 accg[4][4], accu[4][4];
  const f32x4 z4 = {0.f, 0.f, 0.f, 0.f};
#pragma unroll
  for (int i = 0; i < 4; ++i)
#pragma unroll
    for (int j = 0; j < 4; ++j) { accg[i][j] = z4; accu[i][j] = z4; }

  constexpr int NT = Dn / 32;

  auto stage = [&](int t) {
    const int bi = t - (t / 3) * 3;
    const int k0 = t * 32;
#pragma unroll
    for (int c = 0; c < 2; ++c) {
      cp16(A  + (size_t)arow[c] * Dn + k0 + chk[c], &As[bi][slab[c]]);
      cp16(Bg + (size_t)brow[c] * Dn + k0 + chk[c], &Gs[bi][slab[c]]);
      cp16(Bu + (size_t)brow[c] * Dn + k0 + chk[c], &Us[bi][slab[c]]);
    }
  };

  stage(0);
  stage(1);
  asm volatile("s_waitcnt vmcnt(6)" ::: "memory");
  asm volatile("s_barrier" ::: "memory");

  for (int t = 0; t < NT; ++t) {
    const int bi = t - (t / 3) * 3;
    if (t + 2 < NT) stage(t + 2);

    bf16x8 af[4], gf[4], uf[4];
#pragma unroll
    for (int i = 0; i < 4; ++i) {
      const int r2 = wm * 64 + i * 16 + l15;
      af[i] = *(const bf16x8*)(&As[bi][r2 * 32 + ((quad ^ sw2) * 8)]);
    }
#pragma unroll
    for (int j = 0; j < 4; ++j) {
      const int r2 = wn * 64 + j * 16 + l15;
      gf[j] = *(const bf16x8*)(&Gs[bi][r2 * 32 + ((quad ^ sw2) * 8)]);
      uf[j] = *(const bf16x8*)(&Us[bi][r2 * 32 + ((quad ^ sw2) * 8)]);
    }
    __builtin_amdgcn_s_setprio(1);
#pragma unroll
    for (int i = 0; i < 4; ++i)
#pragma unroll
      for (int j = 0; j < 4; ++j) {
        accg[i][j] = __builtin_amdgcn_mfma_f32_16x16x32_bf16(af[i], gf[j], accg[i][j], 0, 0, 0);
        accu[i][j] = __builtin_amdgcn_mfma_f32_16x16x32_bf16(af[i], uf[j], accu[i][j], 0, 0, 0);
      }
    __builtin_amdgcn_s_setprio(0);

    if (t + 2 < NT) asm volatile("s_waitcnt vmcnt(6)" ::: "memory");
    else            asm volatile("s_waitcnt vmcnt(0)" ::: "memory");
    asm volatile("s_barrier" ::: "memory");
  }

#pragma unroll
  for (int i = 0; i < 4; ++i)
#pragma unroll
    for (int j = 0; j < 4; ++j) {
      const int col = n0 + wn * 64 + j * 16 + l15;
#pragma unroll
      for (int r = 0; r < 4; ++r) {
        const int row = m0 + wm * 64 + i * 16 + quad * 4 + r;
        const float g = accg[i][j][r];
        const float u = accu[i][j][r];
        const float sl = g / (1.f + expf(-g));
        out[(size_t)row * Ipad + col] = (col < In) ? (bf16_t)(sl * u) : (bf16_t)0.f;
      }
    }
}

// ---------------------------------------------------------------- 64x128-tile GEMM (wo)
// m97-style: measured best for the N=1024/K=1024 shape at 2 blocks/CU.
__global__ __launch_bounds__(256) void k_gemm64(
    const bf16_t* __restrict__ A, const bf16_t* __restrict__ Bt,
    const float* __restrict__ bias, const float* __restrict__ resid,
    float* __restrict__ outf, int N, int K, int lda, int ldb, int nN) {
  __shared__ bf16_t As[64 * 64];
  __shared__ bf16_t Bs[128 * 64];
  int mblk, nblk;
  xcd_map(blockIdx.x, Mn / 64, nN, mblk, nblk);
  const int m0 = mblk * 64, n0 = nblk * 128;
  const int tid = threadIdx.x;
  const int lane = tid & 63, wid = tid >> 6;
  const int wc = wid * 32;
  const int l15 = lane & 15, quad = lane >> 4;
  const int sw = l15 & 7;
  const int srow_lo = lane >> 3, pchunk = lane & 7;

  f32x4 acc[4][2];
  const f32x4 z4 = {0.f, 0.f, 0.f, 0.f};
#pragma unroll
  for (int i = 0; i < 4; ++i)
#pragma unroll
    for (int j = 0; j < 2; ++j) acc[i][j] = z4;

  for (int k0 = 0; k0 < K; k0 += 64) {
#pragma unroll
    for (int c = 0; c < 2; ++c) {
      const int r = (wid * 2 + c) * 8 + srow_lo;
      const int gc = pchunk ^ (r & 7);
      cp16(A + (size_t)(m0 + r) * lda + k0 + gc * 8, As + (wid * 2 + c) * 512);
    }
#pragma unroll
    for (int c = 0; c < 4; ++c) {
      const int r = (wid * 4 + c) * 8 + srow_lo;
      const int gc = pchunk ^ (r & 7);
      cp16(Bt + (size_t)(n0 + r) * ldb + k0 + gc * 8, Bs + (wid * 4 + c) * 512);
    }
    __syncthreads();
#pragma unroll
    for (int kh = 0; kh < 2; ++kh) {
      const int ph = ((kh * 4 + quad) ^ sw) * 8;
      bf16x8 af[4], bfr[2];
#pragma unroll
      for (int i = 0; i < 4; ++i)
        af[i] = *(const bf16x8*)(As + (i * 16 + l15) * 64 + ph);
#pragma unroll
      for (int j = 0; j < 2; ++j)
        bfr[j] = *(const bf16x8*)(Bs + (wc + j * 16 + l15) * 64 + ph);
#pragma unroll
      for (int i = 0; i < 4; ++i)
#pragma unroll
        for (int j = 0; j < 2; ++j)
          acc[i][j] = __builtin_amdgcn_mfma_f32_16x16x32_bf16(af[i], bfr[j], acc[i][j], 0, 0, 0);
    }
    __syncthreads();
  }

#pragma unroll
  for (int i = 0; i < 4; ++i)
#pragma unroll
    for (int j = 0; j < 2; ++j) {
      const int col = n0 + wc + j * 16 + l15;
      const float bval = bias ? bias[col] : 0.f;
#pragma unroll
      for (int r = 0; r < 4; ++r) {
        const int row = m0 + i * 16 + quad * 4 + r;
        const size_t idx = (size_t)row * N + col;
        outf[idx] = acc[i][j][r] + bval + (resid ? resid[idx] : 0.f);
      }
    }
}

// ---------------------------------------------------------------- MFMA flash attention v3
__global__ __launch_bounds__(256) void k_attn(
    const bf16_t* __restrict__ qkv, bf16_t* __restrict__ Ob) {
  const int qt = (int)gridDim.x - 1 - (int)blockIdx.x;  // LPT
  const int h  = blockIdx.y;
  const int b  = blockIdx.z;
  constexpr int LDK = 72, LDP = 76;
  __shared__ bf16_t Ks[64 * LDK];      // [kseq][d]
  __shared__ bf16_t Vt[64 * LDK];      // [d][kseq]
  __shared__ bf16_t Ps[4][32 * LDP];   // per-wave P [qrow][kseq]

  const int tid  = threadIdx.x;
  const int lane = tid & 63, w = tid >> 6;
  const int l15  = lane & 15, quad = lane >> 4;

  constexpr float L2E = 1.4426950408889634f;
  const float slopeL = -exp2f(-0.5f * (float)(h + 1)) * L2E;

  bf16x8 aq[2][2];
#pragma unroll
  for (int g = 0; g < 2; ++g) {
    const int row = qt * 128 + w * 32 + g * 16 + l15;
    const bf16_t* qp = qkv + (size_t)(b * Sn + row) * 3072 + h * 64;
    aq[g][0] = *(const bf16x8*)(qp + quad * 8);
    aq[g][1] = *(const bf16x8*)(qp + 32 + quad * 8);
#pragma unroll
    for (int e = 0; e < 8; ++e) {
      aq[g][0][e] = (bf16_t)((float)aq[g][0][e] * 0.125f);
      aq[g][1][e] = (bf16_t)((float)aq[g][1][e] * 0.125f);
    }
  }

  int qrow[2];
  float rowterm[2][4];
#pragma unroll
  for (int g = 0; g < 2; ++g) {
    qrow[g] = qt * 128 + w * 32 + g * 16 + quad * 4;
#pragma unroll
    for (int rr = 0; rr < 4; ++rr) rowterm[g][rr] = slopeL * (float)(qrow[g] + rr);
  }
  float colbase[4];
#pragma unroll
  for (int t = 0; t < 4; ++t) colbase[t] = slopeL * (float)(t * 16 + l15);

  f32x4 o[2][4], lacc[2];
  const f32x4 z4 = {0.f, 0.f, 0.f, 0.f};
#pragma unroll
  for (int g = 0; g < 2; ++g) {
    lacc[g] = z4;
#pragma unroll
    for (int dt = 0; dt < 4; ++dt) o[g][dt] = z4;
  }
  bf16x8 ones;
#pragma unroll
  for (int e = 0; e < 8; ++e) ones[e] = (bf16_t)1.0f;

  const int r = tid >> 2, c0e = (tid & 3) * 16;
  const size_t kbase = (size_t)(b * Sn + r) * 3072 + 1024 + h * 64 + c0e;
  const size_t step  = (size_t)64 * 3072;

  s16x8 kr0 = *(const s16x8*)(qkv + kbase);
  s16x8 kr1 = *(const s16x8*)(qkv + kbase + 8);
  s16x8 vr0 = *(const s16x8*)(qkv + kbase + 1024);
  s16x8 vr1 = *(const s16x8*)(qkv + kbase + 1024 + 8);

  const int nkt = 2 * qt + 2;
  for (int kt = 0; kt < nkt; ++kt) {
    __syncthreads();
    *(s16x8*)(Ks + r * LDK + c0e)     = kr0;
    *(s16x8*)(Ks + r * LDK + c0e + 8) = kr1;
    {
      const bf16x8 v0 = *(const bf16x8*)&vr0, v1 = *(const bf16x8*)&vr1;
#pragma unroll
      for (int e = 0; e < 8; ++e) {
        Vt[(c0e + e) * LDK + r]     = v0[e];
        Vt[(c0e + 8 + e) * LDK + r] = v1[e];
      }
    }
    __syncthreads();
    if (kt + 1 < nkt) {
      const size_t kb = kbase + (size_t)(kt + 1) * step;
      kr0 = *(const s16x8*)(qkv + kb);
      kr1 = *(const s16x8*)(qkv + kb + 8);
      vr0 = *(const s16x8*)(qkv + kb + 1024);
      vr1 = *(const s16x8*)(qkv + kb + 1024 + 8);
    }

    const float kofs = slopeL * (float)(kt * 64);
    const bool diag = (kt + 2 >= nkt);

#pragma unroll
    for (int g = 0; g < 2; ++g) {
      f32x4 s[4];
#pragma unroll
      for (int t = 0; t < 4; ++t) s[t] = z4;
#pragma unroll
      for (int t = 0; t < 4; ++t) {
        bf16x8 bk0 = *(const bf16x8*)(Ks + (t * 16 + l15) * LDK + quad * 8);
        bf16x8 bk1 = *(const bf16x8*)(Ks + (t * 16 + l15) * LDK + 32 + quad * 8);
        s[t] = __builtin_amdgcn_mfma_f32_16x16x32_bf16(aq[g][0], bk0, s[t], 0, 0, 0);
        s[t] = __builtin_amdgcn_mfma_f32_16x16x32_bf16(aq[g][1], bk1, s[t], 0, 0, 0);
      }
#pragma unroll
      for (int t = 0; t < 4; ++t) {
        const int j = kt * 64 + t * 16 + l15;
#pragma unroll
        for (int rr = 0; rr < 4; ++rr) {
          float v2 = fmaf(s[t][rr], L2E, rowterm[g][rr] - (kofs + colbase[t]));
          if (diag && j > qrow[g] + rr) v2 = -3.0e38f;
          Ps[w][(g * 16 + quad * 4 + rr) * LDP + t * 16 + l15] = (bf16_t)exp2f(v2);
        }
      }
    }

#pragma unroll
    for (int g = 0; g < 2; ++g) {
#pragma unroll
      for (int kh = 0; kh < 2; ++kh) {
        bf16x8 pa = *(const bf16x8*)(Ps[w] + (g * 16 + l15) * LDP + kh * 32 + quad * 8);
        lacc[g] = __builtin_amdgcn_mfma_f32_16x16x32_bf16(pa, ones, lacc[g], 0, 0, 0);
#pragma unroll
        for (int dt = 0; dt < 4; ++dt) {
          bf16x8 bv = *(const bf16x8*)(Vt + (dt * 16 + l15) * LDK + kh * 32 + quad * 8);
          o[g][dt] = __builtin_amdgcn_mfma_f32_16x16x32_bf16(pa, bv, o[g][dt], 0, 0, 0);
        }
      }
    }
  }

#pragma unroll
  for (int g = 0; g < 2; ++g)
#pragma unroll
    for (int rr = 0; rr < 4; ++rr) {
      const float inv = 1.f / lacc[g][rr];
      bf16_t* op = Ob + (size_t)(b * Sn + qrow[g] + rr) * 1024 + h * 64;
#pragma unroll
      for (int dt = 0; dt < 4; ++dt)
        op[dt * 16 + l15] = (bf16_t)(o[g][dt][rr] * inv);
    }
}

// ---------------------------------------------------------------- launch
extern "C" void kernel_launch(void* const* d_in, const int* in_sizes, int n_in,
                              void* d_out, int out_size, void* d_ws, size_t ws_size,
                              hipStream_t stream) {
  (void)in_sizes; (void)n_in; (void)out_size; (void)ws_size;
  const float* x   = (const float*)d_in[0];
  const float* wq  = (const float*)d_in[1];
  const float* bq  = (const float*)d_in[2];
  const float* wk_ = (const float*)d_in[3];
  const float* bk  = (const float*)d_in[4];
  const float* wv  = (const float*)d_in[5];
  const float* bv  = (const float*)d_in[6];
  const float* wo  = (const float*)d_in[7];
  const float* bo  = (const float*)d_in[8];
  const float* wg  = (const float*)d_in[9];
  const float* wu  = (const float*)d_in[10];
  const float* wd  = (const float*)d_in[11];
  const float* ln1 = (const float*)d_in[12];
  const float* ln2 = (const float*)d_in[13];

  char* base = (char*)d_ws;
  const size_t MiB = 1024 * 1024;
  bf16_t* h1    = (bf16_t*)(base);              // 8 MiB
  bf16_t* wqkvT = (bf16_t*)(base + 8   * MiB);  // 6 MiB
  bf16_t* woT   = (bf16_t*)(base + 16  * MiB);  // 2 MiB
  bf16_t* wgT   = (bf16_t*)(base + 24  * MiB);  // 7.33 MiB
  bf16_t* wuT   = (bf16_t*)(base + 32  * MiB);  // 7.33 MiB
  bf16_t* wdT   = (bf16_t*)(base + 40  * MiB);  // 7.33 MiB
  bf16_t* qkvb  = (bf16_t*)(base + 48  * MiB);  // 24 MiB [M][3072]
  float*  res1  = (float*) (base + 72  * MiB);  // 16 MiB f32
  bf16_t* mlp   = (bf16_t*)(base + 88  * MiB);  // 30 MiB [M][3840]
  float*  parts = (float*) (base + 120 * MiB);  // 32 MiB: two f32 partials
  bf16_t* attnb = (bf16_t*)d_out;               // d_out as bf16 scratch
  bf16_t* h2    = (bf16_t*)d_out;

  const dim3 blk(256);

  // 1. all weight transposes in one packed launch
  TransJobs jobs;
  int start = 0;
  auto setjob = [&](int idx, const float* s, bf16_t* d, int R, int C) {
    const int bx = (C + 31) / 32, by = (R + 31) / 32;
    jobs.j[idx] = {s, d, R, C, bx, start};
    start += bx * by;
  };
  setjob(0, wq,  wqkvT,                       Dn, Dn);
  setjob(1, wk_, wqkvT + (size_t)Dn * Dn,     Dn, Dn);
  setjob(2, wv,  wqkvT + 2 * (size_t)Dn * Dn, Dn, Dn);
  setjob(3, wo,  woT, Dn, Dn);
  setjob(4, wg,  wgT, Dn, In);
  setjob(5, wu,  wuT, Dn, In);
  setjob(6, wd,  wdT, In, Dn);
  k_transpose_all<<<dim3(start), blk, 0, stream>>>(jobs);

  // 2. h1 = bf16(rmsnorm(x, ln1))
  k_rmsnorm<<<dim3(Mn), blk, 0, stream>>>(x, ln1, h1);

  // 3. qkvb = h1 @ wqkvT^T + bias  (256x128 pipelined, 384 blocks, 2/CU)
  k_gemm256x128<0><<<dim3(Mn / 256, 3072 / 128), blk, 0, stream>>>(
      h1, wqkvT, bq, bk, bv, qkvb, Dn, Dn);

  // 4. flash attention (BM=128) -> attnb (d_out scratch)
  k_attn<<<dim3(Sn / 128, Hn, Bn), blk, 0, stream>>>(qkvb, attnb);

  // 5. res1 = attn @ wo^T + bo + x  (m97-style k_gemm64: measured best here)
  k_gemm64<<<dim3((Mn / 64) * (Dn / 128)), blk, 0, stream>>>(
      attnb, woT, bo, x, res1, Dn, Dn, Dn, Dn, Dn / 128);

  // 6. h2 = bf16(rmsnorm(res1, ln2))
  k_rmsnorm<<<dim3(Mn), blk, 0, stream>>>(res1, ln2, h2);

  // 7. mlp = silu(h2@wg)*(h2@wu) in ONE pipelined kernel, zero-padded cols
  k_gateup<<<dim3(Mn / 128, Ipad / 128), blk, 0, stream>>>(h2, wgT, wuT, mlp);

  // 8a. split-K down-proj partials (256x128 pipelined, 256 blocks, 2/CU)
  k_gemm256x128<1><<<dim3(Mn / 256, Dn / 128, 2), blk, 0, stream>>>(
      mlp, wdT, nullptr, nullptr, nullptr, parts, Ipad, In);

  // 8b. d_out = part0 + part1 + res1
  k_combine<<<dim3((Mn * Dn) / 1024), blk, 0, stream>>>(
      parts, parts + (size_t)Mn * Dn, res1, (float*)d_out);
}

// Round 10
// 679.529 us; speedup vs baseline: 1.0307x; 1.0307x over previous
//
#include <hip/hip_runtime.h>
#include <hip/hip_bf16.h>
#include <cmath>

typedef __bf16 bf16_t;
typedef __bf16 bf16x8 __attribute__((ext_vector_type(8)));
typedef short  s16x8  __attribute__((ext_vector_type(8)));
typedef float  f32x4  __attribute__((ext_vector_type(4)));

static constexpr int Bn  = 2;
static constexpr int Sn  = 2048;
static constexpr int Dn  = 1024;
static constexpr int Hn  = 16;
static constexpr int In  = 3752;
static constexpr int Mn  = Bn * Sn;   // 4096 rows
static constexpr int Ipad = 3840;     // In padded to 128

// async 16B global->LDS copy: lane i's 16B lands at ldsbase + i*16 (m97/m104).
__device__ __forceinline__ void cp16(const bf16_t* g, bf16_t* l) {
  __builtin_amdgcn_global_load_lds(
      (const __attribute__((address_space(1))) unsigned int*)g,
      (__attribute__((address_space(3))) unsigned int*)l, 16, 0, 0);
}

// XCD-aware bijective block swizzle (measured neutral, harmless; kept for k_gemm64)
__device__ __forceinline__ void xcd_map(int bid, int nM, int nN, int& m, int& n) {
  const int q = (nM * nN) >> 3;
  const int L = (bid & 7) * q + (bid >> 3);
  const int bandw = nN << 3;
  const int band = L / bandw;
  const int rem  = L - band * bandw;
  n = rem >> 3;
  m = (band << 3) + (rem & 7);
}

// ---------------------------------------------------------------- batched transpose + cast
struct TransJob  { const float* src; bf16_t* dst; int R, C, bx, start; };
struct TransJobs { TransJob j[7]; };

__global__ __launch_bounds__(256) void k_transpose_all(TransJobs jobs) {
  const int bid = blockIdx.x;
  int jj = 0;
#pragma unroll
  for (int t = 1; t < 7; ++t)
    if (bid >= jobs.j[t].start) jj = t;
  const TransJob jb = jobs.j[jj];
  const int local = bid - jb.start;
  const int r0 = (local / jb.bx) * 32, c0 = (local % jb.bx) * 32;
  __shared__ float tile[32][33];
  const int tx = threadIdx.x & 31, ty = threadIdx.x >> 5;
#pragma unroll
  for (int e = 0; e < 4; ++e) {
    int r = r0 + ty + e * 8, c = c0 + tx;
    if (r < jb.R && c < jb.C) tile[ty + e * 8][tx] = jb.src[(size_t)r * jb.C + c];
  }
  __syncthreads();
#pragma unroll
  for (int e = 0; e < 4; ++e) {
    int c = c0 + ty + e * 8, r = r0 + tx;
    if (r < jb.R && c < jb.C) jb.dst[(size_t)c * jb.R + r] = (bf16_t)tile[tx][ty + e * 8];
  }
}

// ---------------------------------------------------------------- rmsnorm (f32 -> bf16)
__global__ __launch_bounds__(256) void k_rmsnorm(const float* __restrict__ in,
                                                 const float* __restrict__ w,
                                                 bf16_t* __restrict__ out) {
  const int row = blockIdx.x;
  const int tid = threadIdx.x;
  const float* ip = in + (size_t)row * Dn;
  float v[4];
  float ss = 0.f;
#pragma unroll
  for (int e = 0; e < 4; ++e) {
    v[e] = ip[tid + e * 256];
    ss += v[e] * v[e];
  }
  for (int off = 32; off > 0; off >>= 1) ss += __shfl_down(ss, off);
  __shared__ float red[4];
  if ((tid & 63) == 0) red[tid >> 6] = ss;
  __syncthreads();
  float tot = red[0] + red[1] + red[2] + red[3];
  float sc = rsqrtf(tot * (1.0f / Dn) + 1e-6f);
  bf16_t* op = out + (size_t)row * Dn;
#pragma unroll
  for (int e = 0; e < 4; ++e) {
    int idx = tid + e * 256;
    op[idx] = (bf16_t)(w[idx] * v[e] * sc);
  }
}

// ---------------------------------------------------------------- qkv GEMM: 128x128 pipelined
// (verified R6) 256 threads, 4 waves (64x64 wave tile), BK=32, 3 LDS buffers,
// depth-2 prefetch, counted vmcnt(4). Epilogue: 3-way bias, bf16 out ld 3072.
__global__ __launch_bounds__(256, 2) void k_gemm128b(
    const bf16_t* __restrict__ A, const bf16_t* __restrict__ Bt,
    const float* __restrict__ b0, const float* __restrict__ b1,
    const float* __restrict__ b2, bf16_t* __restrict__ out) {
  __shared__ bf16_t As[3][128 * 32];
  __shared__ bf16_t Bs[3][128 * 32];
  const int m0 = blockIdx.x * 128, n0 = blockIdx.y * 128;
  const int tid = threadIdx.x;
  const int lane = tid & 63, w = tid >> 6;
  const int wm = w >> 1, wn = w & 1;
  const int l15 = lane & 15, quad = lane >> 4;
  const int sw2 = (l15 >> 1) & 3;

  int row_[2], chk[2], slab[2];
#pragma unroll
  for (int c = 0; c < 2; ++c) {
    const int r = (tid >> 2) + 64 * c;
    row_[c] = r;
    chk[c]  = ((tid & 3) ^ ((r >> 1) & 3)) * 8;
    slab[c] = c * 2048 + w * 512;
  }

  f32x4 acc[4][4];
  const f32x4 z4 = {0.f, 0.f, 0.f, 0.f};
#pragma unroll
  for (int i = 0; i < 4; ++i)
#pragma unroll
    for (int j = 0; j < 4; ++j) acc[i][j] = z4;

  constexpr int NT = Dn / 32;

  auto stage = [&](int t) {
    const int bi = t - (t / 3) * 3;
    const int k0 = t * 32;
#pragma unroll
    for (int c = 0; c < 2; ++c) {
      cp16(A  + (size_t)(m0 + row_[c]) * Dn + k0 + chk[c], &As[bi][slab[c]]);
      cp16(Bt + (size_t)(n0 + row_[c]) * Dn + k0 + chk[c], &Bs[bi][slab[c]]);
    }
  };

  stage(0);
  stage(1);
  asm volatile("s_waitcnt vmcnt(4)" ::: "memory");
  asm volatile("s_barrier" ::: "memory");

  for (int t = 0; t < NT; ++t) {
    const int bi = t - (t / 3) * 3;
    if (t + 2 < NT) stage(t + 2);

    bf16x8 af[4], bfr[4];
#pragma unroll
    for (int i = 0; i < 4; ++i) {
      const int r2 = wm * 64 + i * 16 + l15;
      af[i] = *(const bf16x8*)(&As[bi][r2 * 32 + ((quad ^ sw2) * 8)]);
    }
#pragma unroll
    for (int j = 0; j < 4; ++j) {
      const int r2 = wn * 64 + j * 16 + l15;
      bfr[j] = *(const bf16x8*)(&Bs[bi][r2 * 32 + ((quad ^ sw2) * 8)]);
    }
    __builtin_amdgcn_s_setprio(1);
#pragma unroll
    for (int i = 0; i < 4; ++i)
#pragma unroll
      for (int j = 0; j < 4; ++j)
        acc[i][j] = __builtin_amdgcn_mfma_f32_16x16x32_bf16(af[i], bfr[j], acc[i][j], 0, 0, 0);
    __builtin_amdgcn_s_setprio(0);

    if (t + 2 < NT) asm volatile("s_waitcnt vmcnt(4)" ::: "memory");
    else            asm volatile("s_waitcnt vmcnt(0)" ::: "memory");
    asm volatile("s_barrier" ::: "memory");
  }

#pragma unroll
  for (int i = 0; i < 4; ++i)
#pragma unroll
    for (int j = 0; j < 4; ++j) {
      const int col = n0 + wn * 64 + j * 16 + l15;   // 0..3071, sel uniform per 16-tile
      const int sel = col >> 10;
      const float bval = (sel == 0) ? b0[col] : (sel == 1) ? b1[col - 1024] : b2[col - 2048];
#pragma unroll
      for (int r = 0; r < 4; ++r) {
        const int row = m0 + wm * 64 + i * 16 + quad * 4 + r;
        out[(size_t)row * 3072 + col] = (bf16_t)(acc[i][j][r] + bval);
      }
    }
}

// ---------------------------------------------------------------- down-proj: split-K pipelined
// (verified R7) 128x128/64x64-wave schedule; blockIdx.z picks a K-slice of
// Ipad/2 (60 K-steps), writes f32 partial at part + z*Mn*Dn. Grid 32x8x2 =
// 512 blocks -> 2-3 blocks/CU.
__global__ __launch_bounds__(256, 2) void k_gemm128s(
    const bf16_t* __restrict__ A, const bf16_t* __restrict__ Bt,
    float* __restrict__ part, int lda, int ldb) {
  __shared__ bf16_t As[3][128 * 32];
  __shared__ bf16_t Bs[3][128 * 32];
  const int m0 = blockIdx.x * 128, n0 = blockIdx.y * 128;
  const int kbase = blockIdx.z * (Ipad / 2);
  float* outp = part + (size_t)blockIdx.z * Mn * Dn;
  const int tid = threadIdx.x;
  const int lane = tid & 63, w = tid >> 6;
  const int wm = w >> 1, wn = w & 1;
  const int l15 = lane & 15, quad = lane >> 4;
  const int sw2 = (l15 >> 1) & 3;

  int row_[2], chk[2], slab[2];
#pragma unroll
  for (int c = 0; c < 2; ++c) {
    const int r = (tid >> 2) + 64 * c;
    row_[c] = r;
    chk[c]  = ((tid & 3) ^ ((r >> 1) & 3)) * 8;
    slab[c] = c * 2048 + w * 512;
  }

  f32x4 acc[4][4];
  const f32x4 z4 = {0.f, 0.f, 0.f, 0.f};
#pragma unroll
  for (int i = 0; i < 4; ++i)
#pragma unroll
    for (int j = 0; j < 4; ++j) acc[i][j] = z4;

  constexpr int NT = (Ipad / 2) / 32;   // 60

  auto stage = [&](int t) {
    const int bi = t - (t / 3) * 3;
    const int k0 = kbase + t * 32;
#pragma unroll
    for (int c = 0; c < 2; ++c) {
      cp16(A  + (size_t)(m0 + row_[c]) * lda + k0 + chk[c], &As[bi][slab[c]]);
      cp16(Bt + (size_t)(n0 + row_[c]) * ldb + k0 + chk[c], &Bs[bi][slab[c]]);
    }
  };

  stage(0);
  stage(1);
  asm volatile("s_waitcnt vmcnt(4)" ::: "memory");
  asm volatile("s_barrier" ::: "memory");

  for (int t = 0; t < NT; ++t) {
    const int bi = t - (t / 3) * 3;
    if (t + 2 < NT) stage(t + 2);

    bf16x8 af[4], bfr[4];
#pragma unroll
    for (int i = 0; i < 4; ++i) {
      const int r2 = wm * 64 + i * 16 + l15;
      af[i] = *(const bf16x8*)(&As[bi][r2 * 32 + ((quad ^ sw2) * 8)]);
    }
#pragma unroll
    for (int j = 0; j < 4; ++j) {
      const int r2 = wn * 64 + j * 16 + l15;
      bfr[j] = *(const bf16x8*)(&Bs[bi][r2 * 32 + ((quad ^ sw2) * 8)]);
    }
    __builtin_amdgcn_s_setprio(1);
#pragma unroll
    for (int i = 0; i < 4; ++i)
#pragma unroll
      for (int j = 0; j < 4; ++j)
        acc[i][j] = __builtin_amdgcn_mfma_f32_16x16x32_bf16(af[i], bfr[j], acc[i][j], 0, 0, 0);
    __builtin_amdgcn_s_setprio(0);

    if (t + 2 < NT) asm volatile("s_waitcnt vmcnt(4)" ::: "memory");
    else            asm volatile("s_waitcnt vmcnt(0)" ::: "memory");
    asm volatile("s_barrier" ::: "memory");
  }

#pragma unroll
  for (int i = 0; i < 4; ++i)
#pragma unroll
    for (int j = 0; j < 4; ++j) {
      const int col = n0 + wn * 64 + j * 16 + l15;
#pragma unroll
      for (int r = 0; r < 4; ++r) {
        const int row = m0 + wm * 64 + i * 16 + quad * 4 + r;
        outp[(size_t)row * Dn + col] = acc[i][j][r];
      }
    }
}

// out = a + b + c (f32, vectorized) — split-K combine with residual
__global__ __launch_bounds__(256) void k_combine(
    const float* __restrict__ a, const float* __restrict__ b,
    const float* __restrict__ c, float* __restrict__ out) {
  const size_t i = ((size_t)blockIdx.x * 256 + threadIdx.x) * 4;
  const f32x4 va = *(const f32x4*)(a + i);
  const f32x4 vb = *(const f32x4*)(b + i);
  const f32x4 vc = *(const f32x4*)(c + i);
  f32x4 vo;
#pragma unroll
  for (int e = 0; e < 4; ++e) vo[e] = va[e] + vb[e] + vc[e];
  *(f32x4*)(out + i) = vo;
}

// ---------------------------------------------------------------- fused gate/up, 128x128 pipelined
// (verified R3) 256 threads, BK=32, 3 LDS buffers, depth-2, counted vmcnt(6).
__global__ __launch_bounds__(256, 2) void k_gateup(
    const bf16_t* __restrict__ A, const bf16_t* __restrict__ Bg,
    const bf16_t* __restrict__ Bu, bf16_t* __restrict__ out) {
  __shared__ bf16_t As[3][128 * 32];
  __shared__ bf16_t Gs[3][128 * 32];
  __shared__ bf16_t Us[3][128 * 32];
  const int m0 = blockIdx.x * 128, n0 = blockIdx.y * 128;
  const int tid = threadIdx.x;
  const int lane = tid & 63, w = tid >> 6;
  const int wm = w >> 1, wn = w & 1;
  const int l15 = lane & 15, quad = lane >> 4;
  const int sw2 = (l15 >> 1) & 3;

  int arow[2], brow[2], chk[2], slab[2];
#pragma unroll
  for (int c = 0; c < 2; ++c) {
    const int r = (tid >> 2) + 64 * c;
    arow[c] = m0 + r;
    brow[c] = min(n0 + r, In - 1);
    chk[c]  = ((tid & 3) ^ ((r >> 1) & 3)) * 8;
    slab[c] = c * 2048 + w * 512;
  }

  f32x4 accg[4][4], accu[4][4];
  const f32x4 z4 = {0.f, 0.f, 0.f, 0.f};
#pragma unroll
  for (int i = 0; i < 4; ++i)
#pragma unroll
    for (int j = 0; j < 4; ++j) { accg[i][j] = z4; accu[i][j] = z4; }

  constexpr int NT = Dn / 32;

  auto stage = [&](int t) {
    const int bi = t - (t / 3) * 3;
    const int k0 = t * 32;
#pragma unroll
    for (int c = 0; c < 2; ++c) {
      cp16(A  + (size_t)arow[c] * Dn + k0 + chk[c], &As[bi][slab[c]]);
      cp16(Bg + (size_t)brow[c] * Dn + k0 + chk[c], &Gs[bi][slab[c]]);
      cp16(Bu + (size_t)brow[c] * Dn + k0 + chk[c], &Us[bi][slab[c]]);
    }
  };

  stage(0);
  stage(1);
  asm volatile("s_waitcnt vmcnt(6)" ::: "memory");
  asm volatile("s_barrier" ::: "memory");

  for (int t = 0; t < NT; ++t) {
    const int bi = t - (t / 3) * 3;
    if (t + 2 < NT) stage(t + 2);

    bf16x8 af[4], gf[4], uf[4];
#pragma unroll
    for (int i = 0; i < 4; ++i) {
      const int r2 = wm * 64 + i * 16 + l15;
      af[i] = *(const bf16x8*)(&As[bi][r2 * 32 + ((quad ^ sw2) * 8)]);
    }
#pragma unroll
    for (int j = 0; j < 4; ++j) {
      const int r2 = wn * 64 + j * 16 + l15;
      gf[j] = *(const bf16x8*)(&Gs[bi][r2 * 32 + ((quad ^ sw2) * 8)]);
      uf[j] = *(const bf16x8*)(&Us[bi][r2 * 32 + ((quad ^ sw2) * 8)]);
    }
    __builtin_amdgcn_s_setprio(1);
#pragma unroll
    for (int i = 0; i < 4; ++i)
#pragma unroll
      for (int j = 0; j < 4; ++j) {
        accg[i][j] = __builtin_amdgcn_mfma_f32_16x16x32_bf16(af[i], gf[j], accg[i][j], 0, 0, 0);
        accu[i][j] = __builtin_amdgcn_mfma_f32_16x16x32_bf16(af[i], uf[j], accu[i][j], 0, 0, 0);
      }
    __builtin_amdgcn_s_setprio(0);

    if (t + 2 < NT) asm volatile("s_waitcnt vmcnt(6)" ::: "memory");
    else            asm volatile("s_waitcnt vmcnt(0)" ::: "memory");
    asm volatile("s_barrier" ::: "memory");
  }

#pragma unroll
  for (int i = 0; i < 4; ++i)
#pragma unroll
    for (int j = 0; j < 4; ++j) {
      const int col = n0 + wn * 64 + j * 16 + l15;
#pragma unroll
      for (int r = 0; r < 4; ++r) {
        const int row = m0 + wm * 64 + i * 16 + quad * 4 + r;
        const float g = accg[i][j][r];
        const float u = accu[i][j][r];
        const float sl = g / (1.f + expf(-g));
        out[(size_t)row * Ipad + col] = (col < In) ? (bf16_t)(sl * u) : (bf16_t)0.f;
      }
    }
}

// ---------------------------------------------------------------- 64x128-tile GEMM (wo)
// m97-style: measured best for the N=1024/K=1024 shape at 2 blocks/CU.
__global__ __launch_bounds__(256) void k_gemm64(
    const bf16_t* __restrict__ A, const bf16_t* __restrict__ Bt,
    const float* __restrict__ bias, const float* __restrict__ resid,
    float* __restrict__ outf, int N, int K, int lda, int ldb, int nN) {
  __shared__ bf16_t As[64 * 64];
  __shared__ bf16_t Bs[128 * 64];
  int mblk, nblk;
  xcd_map(blockIdx.x, Mn / 64, nN, mblk, nblk);
  const int m0 = mblk * 64, n0 = nblk * 128;
  const int tid = threadIdx.x;
  const int lane = tid & 63, wid = tid >> 6;
  const int wc = wid * 32;
  const int l15 = lane & 15, quad = lane >> 4;
  const int sw = l15 & 7;
  const int srow_lo = lane >> 3, pchunk = lane & 7;

  f32x4 acc[4][2];
  const f32x4 z4 = {0.f, 0.f, 0.f, 0.f};
#pragma unroll
  for (int i = 0; i < 4; ++i)
#pragma unroll
    for (int j = 0; j < 2; ++j) acc[i][j] = z4;

  for (int k0 = 0; k0 < K; k0 += 64) {
#pragma unroll
    for (int c = 0; c < 2; ++c) {
      const int r = (wid * 2 + c) * 8 + srow_lo;
      const int gc = pchunk ^ (r & 7);
      cp16(A + (size_t)(m0 + r) * lda + k0 + gc * 8, As + (wid * 2 + c) * 512);
    }
#pragma unroll
    for (int c = 0; c < 4; ++c) {
      const int r = (wid * 4 + c) * 8 + srow_lo;
      const int gc = pchunk ^ (r & 7);
      cp16(Bt + (size_t)(n0 + r) * ldb + k0 + gc * 8, Bs + (wid * 4 + c) * 512);
    }
    __syncthreads();
#pragma unroll
    for (int kh = 0; kh < 2; ++kh) {
      const int ph = ((kh * 4 + quad) ^ sw) * 8;
      bf16x8 af[4], bfr[2];
#pragma unroll
      for (int i = 0; i < 4; ++i)
        af[i] = *(const bf16x8*)(As + (i * 16 + l15) * 64 + ph);
#pragma unroll
      for (int j = 0; j < 2; ++j)
        bfr[j] = *(const bf16x8*)(Bs + (wc + j * 16 + l15) * 64 + ph);
#pragma unroll
      for (int i = 0; i < 4; ++i)
#pragma unroll
        for (int j = 0; j < 2; ++j)
          acc[i][j] = __builtin_amdgcn_mfma_f32_16x16x32_bf16(af[i], bfr[j], acc[i][j], 0, 0, 0);
    }
    __syncthreads();
  }

#pragma unroll
  for (int i = 0; i < 4; ++i)
#pragma unroll
    for (int j = 0; j < 2; ++j) {
      const int col = n0 + wc + j * 16 + l15;
      const float bval = bias ? bias[col] : 0.f;
#pragma unroll
      for (int r = 0; r < 4; ++r) {
        const int row = m0 + i * 16 + quad * 4 + r;
        const size_t idx = (size_t)row * N + col;
        outf[idx] = acc[i][j][r] + bval + (resid ? resid[idx] : 0.f);
      }
    }
}

// ---------------------------------------------------------------- MFMA flash attention v3
__global__ __launch_bounds__(256) void k_attn(
    const bf16_t* __restrict__ qkv, bf16_t* __restrict__ Ob) {
  const int qt = (int)gridDim.x - 1 - (int)blockIdx.x;  // LPT
  const int h  = blockIdx.y;
  const int b  = blockIdx.z;
  constexpr int LDK = 72, LDP = 76;
  __shared__ bf16_t Ks[64 * LDK];      // [kseq][d]
  __shared__ bf16_t Vt[64 * LDK];      // [d][kseq]
  __shared__ bf16_t Ps[4][32 * LDP];   // per-wave P [qrow][kseq]

  const int tid  = threadIdx.x;
  const int lane = tid & 63, w = tid >> 6;
  const int l15  = lane & 15, quad = lane >> 4;

  constexpr float L2E = 1.4426950408889634f;
  const float slopeL = -exp2f(-0.5f * (float)(h + 1)) * L2E;

  bf16x8 aq[2][2];
#pragma unroll
  for (int g = 0; g < 2; ++g) {
    const int row = qt * 128 + w * 32 + g * 16 + l15;
    const bf16_t* qp = qkv + (size_t)(b * Sn + row) * 3072 + h * 64;
    aq[g][0] = *(const bf16x8*)(qp + quad * 8);
    aq[g][1] = *(const bf16x8*)(qp + 32 + quad * 8);
#pragma unroll
    for (int e = 0; e < 8; ++e) {
      aq[g][0][e] = (bf16_t)((float)aq[g][0][e] * 0.125f);
      aq[g][1][e] = (bf16_t)((float)aq[g][1][e] * 0.125f);
    }
  }

  int qrow[2];
  float rowterm[2][4];
#pragma unroll
  for (int g = 0; g < 2; ++g) {
    qrow[g] = qt * 128 + w * 32 + g * 16 + quad * 4;
#pragma unroll
    for (int rr = 0; rr < 4; ++rr) rowterm[g][rr] = slopeL * (float)(qrow[g] + rr);
  }
  float colbase[4];
#pragma unroll
  for (int t = 0; t < 4; ++t) colbase[t] = slopeL * (float)(t * 16 + l15);

  f32x4 o[2][4], lacc[2];
  const f32x4 z4 = {0.f, 0.f, 0.f, 0.f};
#pragma unroll
  for (int g = 0; g < 2; ++g) {
    lacc[g] = z4;
#pragma unroll
    for (int dt = 0; dt < 4; ++dt) o[g][dt] = z4;
  }
  bf16x8 ones;
#pragma unroll
  for (int e = 0; e < 8; ++e) ones[e] = (bf16_t)1.0f;

  const int r = tid >> 2, c0e = (tid & 3) * 16;
  const size_t kbase = (size_t)(b * Sn + r) * 3072 + 1024 + h * 64 + c0e;
  const size_t step  = (size_t)64 * 3072;

  s16x8 kr0 = *(const s16x8*)(qkv + kbase);
  s16x8 kr1 = *(const s16x8*)(qkv + kbase + 8);
  s16x8 vr0 = *(const s16x8*)(qkv + kbase + 1024);
  s16x8 vr1 = *(const s16x8*)(qkv + kbase + 1024 + 8);

  const int nkt = 2 * qt + 2;
  for (int kt = 0; kt < nkt; ++kt) {
    __syncthreads();
    *(s16x8*)(Ks + r * LDK + c0e)     = kr0;
    *(s16x8*)(Ks + r * LDK + c0e + 8) = kr1;
    {
      const bf16x8 v0 = *(const bf16x8*)&vr0, v1 = *(const bf16x8*)&vr1;
#pragma unroll
      for (int e = 0; e < 8; ++e) {
        Vt[(c0e + e) * LDK + r]     = v0[e];
        Vt[(c0e + 8 + e) * LDK + r] = v1[e];
      }
    }
    __syncthreads();
    if (kt + 1 < nkt) {
      const size_t kb = kbase + (size_t)(kt + 1) * step;
      kr0 = *(const s16x8*)(qkv + kb);
      kr1 = *(const s16x8*)(qkv + kb + 8);
      vr0 = *(const s16x8*)(qkv + kb + 1024);
      vr1 = *(const s16x8*)(qkv + kb + 1024 + 8);
    }

    const float kofs = slopeL * (float)(kt * 64);
    const bool diag = (kt + 2 >= nkt);

#pragma unroll
    for (int g = 0; g < 2; ++g) {
      f32x4 s[4];
#pragma unroll
      for (int t = 0; t < 4; ++t) s[t] = z4;
#pragma unroll
      for (int t = 0; t < 4; ++t) {
        bf16x8 bk0 = *(const bf16x8*)(Ks + (t * 16 + l15) * LDK + quad * 8);
        bf16x8 bk1 = *(const bf16x8*)(Ks + (t * 16 + l15) * LDK + 32 + quad * 8);
        s[t] = __builtin_amdgcn_mfma_f32_16x16x32_bf16(aq[g][0], bk0, s[t], 0, 0, 0);
        s[t] = __builtin_amdgcn_mfma_f32_16x16x32_bf16(aq[g][1], bk1, s[t], 0, 0, 0);
      }
#pragma unroll
      for (int t = 0; t < 4; ++t) {
        const int j = kt * 64 + t * 16 + l15;
#pragma unroll
        for (int rr = 0; rr < 4; ++rr) {
          float v2 = fmaf(s[t][rr], L2E, rowterm[g][rr] - (kofs + colbase[t]));
          if (diag && j > qrow[g] + rr) v2 = -3.0e38f;
          Ps[w][(g * 16 + quad * 4 + rr) * LDP + t * 16 + l15] = (bf16_t)exp2f(v2);
        }
      }
    }

#pragma unroll
    for (int g = 0; g < 2; ++g) {
#pragma unroll
      for (int kh = 0; kh < 2; ++kh) {
        bf16x8 pa = *(const bf16x8*)(Ps[w] + (g * 16 + l15) * LDP + kh * 32 + quad * 8);
        lacc[g] = __builtin_amdgcn_mfma_f32_16x16x32_bf16(pa, ones, lacc[g], 0, 0, 0);
#pragma unroll
        for (int dt = 0; dt < 4; ++dt) {
          bf16x8 bv = *(const bf16x8*)(Vt + (dt * 16 + l15) * LDK + kh * 32 + quad * 8);
          o[g][dt] = __builtin_amdgcn_mfma_f32_16x16x32_bf16(pa, bv, o[g][dt], 0, 0, 0);
        }
      }
    }
  }

#pragma unroll
  for (int g = 0; g < 2; ++g)
#pragma unroll
    for (int rr = 0; rr < 4; ++rr) {
      const float inv = 1.f / lacc[g][rr];
      bf16_t* op = Ob + (size_t)(b * Sn + qrow[g] + rr) * 1024 + h * 64;
#pragma unroll
      for (int dt = 0; dt < 4; ++dt)
        op[dt * 16 + l15] = (bf16_t)(o[g][dt][rr] * inv);
    }
}

// ---------------------------------------------------------------- launch
extern "C" void kernel_launch(void* const* d_in, const int* in_sizes, int n_in,
                              void* d_out, int out_size, void* d_ws, size_t ws_size,
                              hipStream_t stream) {
  (void)in_sizes; (void)n_in; (void)out_size; (void)ws_size;
  const float* x   = (const float*)d_in[0];
  const float* wq  = (const float*)d_in[1];
  const float* bq  = (const float*)d_in[2];
  const float* wk_ = (const float*)d_in[3];
  const float* bk  = (const float*)d_in[4];
  const float* wv  = (const float*)d_in[5];
  const float* bv  = (const float*)d_in[6];
  const float* wo  = (const float*)d_in[7];
  const float* bo  = (const float*)d_in[8];
  const float* wg  = (const float*)d_in[9];
  const float* wu  = (const float*)d_in[10];
  const float* wd  = (const float*)d_in[11];
  const float* ln1 = (const float*)d_in[12];
  const float* ln2 = (const float*)d_in[13];

  char* base = (char*)d_ws;
  const size_t MiB = 1024 * 1024;
  bf16_t* h1    = (bf16_t*)(base);              // 8 MiB
  bf16_t* wqkvT = (bf16_t*)(base + 8   * MiB);  // 6 MiB
  bf16_t* woT   = (bf16_t*)(base + 16  * MiB);  // 2 MiB
  bf16_t* wgT   = (bf16_t*)(base + 24  * MiB);  // 7.33 MiB
  bf16_t* wuT   = (bf16_t*)(base + 32  * MiB);  // 7.33 MiB
  bf16_t* wdT   = (bf16_t*)(base + 40  * MiB);  // 7.33 MiB
  bf16_t* qkvb  = (bf16_t*)(base + 48  * MiB);  // 24 MiB [M][3072]
  float*  res1  = (float*) (base + 72  * MiB);  // 16 MiB f32
  bf16_t* mlp   = (bf16_t*)(base + 88  * MiB);  // 30 MiB [M][3840]
  float*  parts = (float*) (base + 120 * MiB);  // 32 MiB: two f32 partials
  bf16_t* attnb = (bf16_t*)d_out;               // d_out as bf16 scratch
  bf16_t* h2    = (bf16_t*)d_out;

  const dim3 blk(256);

  // 1. all weight transposes in one packed launch
  TransJobs jobs;
  int start = 0;
  auto setjob = [&](int idx, const float* s, bf16_t* d, int R, int C) {
    const int bx = (C + 31) / 32, by = (R + 31) / 32;
    jobs.j[idx] = {s, d, R, C, bx, start};
    start += bx * by;
  };
  setjob(0, wq,  wqkvT,                       Dn, Dn);
  setjob(1, wk_, wqkvT + (size_t)Dn * Dn,     Dn, Dn);
  setjob(2, wv,  wqkvT + 2 * (size_t)Dn * Dn, Dn, Dn);
  setjob(3, wo,  woT, Dn, Dn);
  setjob(4, wg,  wgT, Dn, In);
  setjob(5, wu,  wuT, Dn, In);
  setjob(6, wd,  wdT, In, Dn);
  k_transpose_all<<<dim3(start), blk, 0, stream>>>(jobs);

  // 2. h1 = bf16(rmsnorm(x, ln1))
  k_rmsnorm<<<dim3(Mn), blk, 0, stream>>>(x, ln1, h1);

  // 3. qkvb = h1 @ wqkvT^T + bias  (128x128 pipelined, 768 blocks = 3/CU)
  k_gemm128b<<<dim3(Mn / 128, 3072 / 128), blk, 0, stream>>>(
      h1, wqkvT, bq, bk, bv, qkvb);

  // 4. flash attention (BM=128) -> attnb (d_out scratch)
  k_attn<<<dim3(Sn / 128, Hn, Bn), blk, 0, stream>>>(qkvb, attnb);

  // 5. res1 = attn @ wo^T + bo + x  (m97-style k_gemm64: measured best here)
  k_gemm64<<<dim3((Mn / 64) * (Dn / 128)), blk, 0, stream>>>(
      attnb, woT, bo, x, res1, Dn, Dn, Dn, Dn, Dn / 128);

  // 6. h2 = bf16(rmsnorm(res1, ln2))
  k_rmsnorm<<<dim3(Mn), blk, 0, stream>>>(res1, ln2, h2);

  // 7. mlp = silu(h2@wg)*(h2@wu) in ONE pipelined kernel, zero-padded cols
  k_gateup<<<dim3(Mn / 128, Ipad / 128), blk, 0, stream>>>(h2, wgT, wuT, mlp);

  // 8a. split-K down-proj partials (pipelined 128x128, 512 blocks = 2-3/CU)
  k_gemm128s<<<dim3(Mn / 128, Dn / 128, 2), blk, 0, stream>>>(
      mlp, wdT, parts, Ipad, In);

  // 8b. d_out = part0 + part1 + res1
  k_combine<<<dim3((Mn * Dn) / 1024), blk, 0, stream>>>(
      parts, parts + (size_t)Mn * Dn, res1, (float*)d_out);
}

// Round 11
// 672.640 us; speedup vs baseline: 1.0413x; 1.0102x over previous
//
#include <hip/hip_runtime.h>
#include <hip/hip_bf16.h>
#include <cmath>

typedef __bf16 bf16_t;
typedef __bf16 bf16x8 __attribute__((ext_vector_type(8)));
typedef short  s16x8  __attribute__((ext_vector_type(8)));
typedef float  f32x4  __attribute__((ext_vector_type(4)));

static constexpr int Bn  = 2;
static constexpr int Sn  = 2048;
static constexpr int Dn  = 1024;
static constexpr int Hn  = 16;
static constexpr int In  = 3752;
static constexpr int Mn  = Bn * Sn;   // 4096 rows
static constexpr int Ipad = 3840;     // In padded to 128

// async 16B global->LDS copy: lane i's 16B lands at ldsbase + i*16 (m97/m104).
__device__ __forceinline__ void cp16(const bf16_t* g, bf16_t* l) {
  __builtin_amdgcn_global_load_lds(
      (const __attribute__((address_space(1))) unsigned int*)g,
      (__attribute__((address_space(3))) unsigned int*)l, 16, 0, 0);
}

// XCD-aware bijective block swizzle (measured neutral, harmless; kept for k_gemm64)
__device__ __forceinline__ void xcd_map(int bid, int nM, int nN, int& m, int& n) {
  const int q = (nM * nN) >> 3;
  const int L = (bid & 7) * q + (bid >> 3);
  const int bandw = nN << 3;
  const int band = L / bandw;
  const int rem  = L - band * bandw;
  n = rem >> 3;
  m = (band << 3) + (rem & 7);
}

// ---------------------------------------------------------------- batched transpose + cast
struct TransJob  { const float* src; bf16_t* dst; int R, C, bx, start; };
struct TransJobs { TransJob j[7]; };

__global__ __launch_bounds__(256) void k_transpose_all(TransJobs jobs) {
  const int bid = blockIdx.x;
  int jj = 0;
#pragma unroll
  for (int t = 1; t < 7; ++t)
    if (bid >= jobs.j[t].start) jj = t;
  const TransJob jb = jobs.j[jj];
  const int local = bid - jb.start;
  const int r0 = (local / jb.bx) * 32, c0 = (local % jb.bx) * 32;
  __shared__ float tile[32][33];
  const int tx = threadIdx.x & 31, ty = threadIdx.x >> 5;
#pragma unroll
  for (int e = 0; e < 4; ++e) {
    int r = r0 + ty + e * 8, c = c0 + tx;
    if (r < jb.R && c < jb.C) tile[ty + e * 8][tx] = jb.src[(size_t)r * jb.C + c];
  }
  __syncthreads();
#pragma unroll
  for (int e = 0; e < 4; ++e) {
    int c = c0 + ty + e * 8, r = r0 + tx;
    if (r < jb.R && c < jb.C) jb.dst[(size_t)c * jb.R + r] = (bf16_t)tile[tx][ty + e * 8];
  }
}

// ---------------------------------------------------------------- rmsnorm (f32 -> bf16)
__global__ __launch_bounds__(256) void k_rmsnorm(const float* __restrict__ in,
                                                 const float* __restrict__ w,
                                                 bf16_t* __restrict__ out) {
  const int row = blockIdx.x;
  const int tid = threadIdx.x;
  const float* ip = in + (size_t)row * Dn;
  float v[4];
  float ss = 0.f;
#pragma unroll
  for (int e = 0; e < 4; ++e) {
    v[e] = ip[tid + e * 256];
    ss += v[e] * v[e];
  }
  for (int off = 32; off > 0; off >>= 1) ss += __shfl_down(ss, off);
  __shared__ float red[4];
  if ((tid & 63) == 0) red[tid >> 6] = ss;
  __syncthreads();
  float tot = red[0] + red[1] + red[2] + red[3];
  float sc = rsqrtf(tot * (1.0f / Dn) + 1e-6f);
  bf16_t* op = out + (size_t)row * Dn;
#pragma unroll
  for (int e = 0; e < 4; ++e) {
    int idx = tid + e * 256;
    op[idx] = (bf16_t)(w[idx] * v[e] * sc);
  }
}

// ---------------------------------------------------------------- qkv GEMM: 128x128 pipelined
// (verified R6) 256 threads, 4 waves (64x64 wave tile), BK=32, 3 LDS buffers,
// depth-2 prefetch, counted vmcnt(4). Epilogue: 3-way bias, bf16 out ld 3072.
__global__ __launch_bounds__(256, 2) void k_gemm128b(
    const bf16_t* __restrict__ A, const bf16_t* __restrict__ Bt,
    const float* __restrict__ b0, const float* __restrict__ b1,
    const float* __restrict__ b2, bf16_t* __restrict__ out) {
  __shared__ bf16_t As[3][128 * 32];
  __shared__ bf16_t Bs[3][128 * 32];
  const int m0 = blockIdx.x * 128, n0 = blockIdx.y * 128;
  const int tid = threadIdx.x;
  const int lane = tid & 63, w = tid >> 6;
  const int wm = w >> 1, wn = w & 1;
  const int l15 = lane & 15, quad = lane >> 4;
  const int sw2 = (l15 >> 1) & 3;

  int row_[2], chk[2], slab[2];
#pragma unroll
  for (int c = 0; c < 2; ++c) {
    const int r = (tid >> 2) + 64 * c;
    row_[c] = r;
    chk[c]  = ((tid & 3) ^ ((r >> 1) & 3)) * 8;
    slab[c] = c * 2048 + w * 512;
  }

  f32x4 acc[4][4];
  const f32x4 z4 = {0.f, 0.f, 0.f, 0.f};
#pragma unroll
  for (int i = 0; i < 4; ++i)
#pragma unroll
    for (int j = 0; j < 4; ++j) acc[i][j] = z4;

  constexpr int NT = Dn / 32;

  auto stage = [&](int t) {
    const int bi = t - (t / 3) * 3;
    const int k0 = t * 32;
#pragma unroll
    for (int c = 0; c < 2; ++c) {
      cp16(A  + (size_t)(m0 + row_[c]) * Dn + k0 + chk[c], &As[bi][slab[c]]);
      cp16(Bt + (size_t)(n0 + row_[c]) * Dn + k0 + chk[c], &Bs[bi][slab[c]]);
    }
  };

  stage(0);
  stage(1);
  asm volatile("s_waitcnt vmcnt(4)" ::: "memory");
  asm volatile("s_barrier" ::: "memory");

  for (int t = 0; t < NT; ++t) {
    const int bi = t - (t / 3) * 3;
    if (t + 2 < NT) stage(t + 2);

    bf16x8 af[4], bfr[4];
#pragma unroll
    for (int i = 0; i < 4; ++i) {
      const int r2 = wm * 64 + i * 16 + l15;
      af[i] = *(const bf16x8*)(&As[bi][r2 * 32 + ((quad ^ sw2) * 8)]);
    }
#pragma unroll
    for (int j = 0; j < 4; ++j) {
      const int r2 = wn * 64 + j * 16 + l15;
      bfr[j] = *(const bf16x8*)(&Bs[bi][r2 * 32 + ((quad ^ sw2) * 8)]);
    }
    __builtin_amdgcn_s_setprio(1);
#pragma unroll
    for (int i = 0; i < 4; ++i)
#pragma unroll
      for (int j = 0; j < 4; ++j)
        acc[i][j] = __builtin_amdgcn_mfma_f32_16x16x32_bf16(af[i], bfr[j], acc[i][j], 0, 0, 0);
    __builtin_amdgcn_s_setprio(0);

    if (t + 2 < NT) asm volatile("s_waitcnt vmcnt(4)" ::: "memory");
    else            asm volatile("s_waitcnt vmcnt(0)" ::: "memory");
    asm volatile("s_barrier" ::: "memory");
  }

#pragma unroll
  for (int i = 0; i < 4; ++i)
#pragma unroll
    for (int j = 0; j < 4; ++j) {
      const int col = n0 + wn * 64 + j * 16 + l15;   // 0..3071, sel uniform per 16-tile
      const int sel = col >> 10;
      const float bval = (sel == 0) ? b0[col] : (sel == 1) ? b1[col - 1024] : b2[col - 2048];
#pragma unroll
      for (int r = 0; r < 4; ++r) {
        const int row = m0 + wm * 64 + i * 16 + quad * 4 + r;
        out[(size_t)row * 3072 + col] = (bf16_t)(acc[i][j][r] + bval);
      }
    }
}

// ---------------------------------------------------------------- down-proj: split-K pipelined
// (verified R7) 128x128/64x64-wave schedule; blockIdx.z picks a K-slice of
// Ipad/2 (60 K-steps), writes f32 partial at part + z*Mn*Dn. Grid 32x8x2 =
// 512 blocks -> 2-3 blocks/CU.
__global__ __launch_bounds__(256, 2) void k_gemm128s(
    const bf16_t* __restrict__ A, const bf16_t* __restrict__ Bt,
    float* __restrict__ part, int lda, int ldb) {
  __shared__ bf16_t As[3][128 * 32];
  __shared__ bf16_t Bs[3][128 * 32];
  const int m0 = blockIdx.x * 128, n0 = blockIdx.y * 128;
  const int kbase = blockIdx.z * (Ipad / 2);
  float* outp = part + (size_t)blockIdx.z * Mn * Dn;
  const int tid = threadIdx.x;
  const int lane = tid & 63, w = tid >> 6;
  const int wm = w >> 1, wn = w & 1;
  const int l15 = lane & 15, quad = lane >> 4;
  const int sw2 = (l15 >> 1) & 3;

  int row_[2], chk[2], slab[2];
#pragma unroll
  for (int c = 0; c < 2; ++c) {
    const int r = (tid >> 2) + 64 * c;
    row_[c] = r;
    chk[c]  = ((tid & 3) ^ ((r >> 1) & 3)) * 8;
    slab[c] = c * 2048 + w * 512;
  }

  f32x4 acc[4][4];
  const f32x4 z4 = {0.f, 0.f, 0.f, 0.f};
#pragma unroll
  for (int i = 0; i < 4; ++i)
#pragma unroll
    for (int j = 0; j < 4; ++j) acc[i][j] = z4;

  constexpr int NT = (Ipad / 2) / 32;   // 60

  auto stage = [&](int t) {
    const int bi = t - (t / 3) * 3;
    const int k0 = kbase + t * 32;
#pragma unroll
    for (int c = 0; c < 2; ++c) {
      cp16(A  + (size_t)(m0 + row_[c]) * lda + k0 + chk[c], &As[bi][slab[c]]);
      cp16(Bt + (size_t)(n0 + row_[c]) * ldb + k0 + chk[c], &Bs[bi][slab[c]]);
    }
  };

  stage(0);
  stage(1);
  asm volatile("s_waitcnt vmcnt(4)" ::: "memory");
  asm volatile("s_barrier" ::: "memory");

  for (int t = 0; t < NT; ++t) {
    const int bi = t - (t / 3) * 3;
    if (t + 2 < NT) stage(t + 2);

    bf16x8 af[4], bfr[4];
#pragma unroll
    for (int i = 0; i < 4; ++i) {
      const int r2 = wm * 64 + i * 16 + l15;
      af[i] = *(const bf16x8*)(&As[bi][r2 * 32 + ((quad ^ sw2) * 8)]);
    }
#pragma unroll
    for (int j = 0; j < 4; ++j) {
      const int r2 = wn * 64 + j * 16 + l15;
      bfr[j] = *(const bf16x8*)(&Bs[bi][r2 * 32 + ((quad ^ sw2) * 8)]);
    }
    __builtin_amdgcn_s_setprio(1);
#pragma unroll
    for (int i = 0; i < 4; ++i)
#pragma unroll
      for (int j = 0; j < 4; ++j)
        acc[i][j] = __builtin_amdgcn_mfma_f32_16x16x32_bf16(af[i], bfr[j], acc[i][j], 0, 0, 0);
    __builtin_amdgcn_s_setprio(0);

    if (t + 2 < NT) asm volatile("s_waitcnt vmcnt(4)" ::: "memory");
    else            asm volatile("s_waitcnt vmcnt(0)" ::: "memory");
    asm volatile("s_barrier" ::: "memory");
  }

#pragma unroll
  for (int i = 0; i < 4; ++i)
#pragma unroll
    for (int j = 0; j < 4; ++j) {
      const int col = n0 + wn * 64 + j * 16 + l15;
#pragma unroll
      for (int r = 0; r < 4; ++r) {
        const int row = m0 + wm * 64 + i * 16 + quad * 4 + r;
        outp[(size_t)row * Dn + col] = acc[i][j][r];
      }
    }
}

// out = a + b + c (f32, vectorized) — split-K combine with residual
__global__ __launch_bounds__(256) void k_combine(
    const float* __restrict__ a, const float* __restrict__ b,
    const float* __restrict__ c, float* __restrict__ out) {
  const size_t i = ((size_t)blockIdx.x * 256 + threadIdx.x) * 4;
  const f32x4 va = *(const f32x4*)(a + i);
  const f32x4 vb = *(const f32x4*)(b + i);
  const f32x4 vc = *(const f32x4*)(c + i);
  f32x4 vo;
#pragma unroll
  for (int e = 0; e < 4; ++e) vo[e] = va[e] + vb[e] + vc[e];
  *(f32x4*)(out + i) = vo;
}

// ---------------------------------------------------------------- fused gate/up, 128x128 pipelined
// (verified R3) 256 threads, BK=32, 3 LDS buffers, depth-2, counted vmcnt(6).
__global__ __launch_bounds__(256, 2) void k_gateup(
    const bf16_t* __restrict__ A, const bf16_t* __restrict__ Bg,
    const bf16_t* __restrict__ Bu, bf16_t* __restrict__ out) {
  __shared__ bf16_t As[3][128 * 32];
  __shared__ bf16_t Gs[3][128 * 32];
  __shared__ bf16_t Us[3][128 * 32];
  const int m0 = blockIdx.x * 128, n0 = blockIdx.y * 128;
  const int tid = threadIdx.x;
  const int lane = tid & 63, w = tid >> 6;
  const int wm = w >> 1, wn = w & 1;
  const int l15 = lane & 15, quad = lane >> 4;
  const int sw2 = (l15 >> 1) & 3;

  int arow[2], brow[2], chk[2], slab[2];
#pragma unroll
  for (int c = 0; c < 2; ++c) {
    const int r = (tid >> 2) + 64 * c;
    arow[c] = m0 + r;
    brow[c] = min(n0 + r, In - 1);
    chk[c]  = ((tid & 3) ^ ((r >> 1) & 3)) * 8;
    slab[c] = c * 2048 + w * 512;
  }

  f32x4 accg[4][4], accu[4][4];
  const f32x4 z4 = {0.f, 0.f, 0.f, 0.f};
#pragma unroll
  for (int i = 0; i < 4; ++i)
#pragma unroll
    for (int j = 0; j < 4; ++j) { accg[i][j] = z4; accu[i][j] = z4; }

  constexpr int NT = Dn / 32;

  auto stage = [&](int t) {
    const int bi = t - (t / 3) * 3;
    const int k0 = t * 32;
#pragma unroll
    for (int c = 0; c < 2; ++c) {
      cp16(A  + (size_t)arow[c] * Dn + k0 + chk[c], &As[bi][slab[c]]);
      cp16(Bg + (size_t)brow[c] * Dn + k0 + chk[c], &Gs[bi][slab[c]]);
      cp16(Bu + (size_t)brow[c] * Dn + k0 + chk[c], &Us[bi][slab[c]]);
    }
  };

  stage(0);
  stage(1);
  asm volatile("s_waitcnt vmcnt(6)" ::: "memory");
  asm volatile("s_barrier" ::: "memory");

  for (int t = 0; t < NT; ++t) {
    const int bi = t - (t / 3) * 3;
    if (t + 2 < NT) stage(t + 2);

    bf16x8 af[4], gf[4], uf[4];
#pragma unroll
    for (int i = 0; i < 4; ++i) {
      const int r2 = wm * 64 + i * 16 + l15;
      af[i] = *(const bf16x8*)(&As[bi][r2 * 32 + ((quad ^ sw2) * 8)]);
    }
#pragma unroll
    for (int j = 0; j < 4; ++j) {
      const int r2 = wn * 64 + j * 16 + l15;
      gf[j] = *(const bf16x8*)(&Gs[bi][r2 * 32 + ((quad ^ sw2) * 8)]);
      uf[j] = *(const bf16x8*)(&Us[bi][r2 * 32 + ((quad ^ sw2) * 8)]);
    }
    __builtin_amdgcn_s_setprio(1);
#pragma unroll
    for (int i = 0; i < 4; ++i)
#pragma unroll
      for (int j = 0; j < 4; ++j) {
        accg[i][j] = __builtin_amdgcn_mfma_f32_16x16x32_bf16(af[i], gf[j], accg[i][j], 0, 0, 0);
        accu[i][j] = __builtin_amdgcn_mfma_f32_16x16x32_bf16(af[i], uf[j], accu[i][j], 0, 0, 0);
      }
    __builtin_amdgcn_s_setprio(0);

    if (t + 2 < NT) asm volatile("s_waitcnt vmcnt(6)" ::: "memory");
    else            asm volatile("s_waitcnt vmcnt(0)" ::: "memory");
    asm volatile("s_barrier" ::: "memory");
  }

#pragma unroll
  for (int i = 0; i < 4; ++i)
#pragma unroll
    for (int j = 0; j < 4; ++j) {
      const int col = n0 + wn * 64 + j * 16 + l15;
#pragma unroll
      for (int r = 0; r < 4; ++r) {
        const int row = m0 + wm * 64 + i * 16 + quad * 4 + r;
        const float g = accg[i][j][r];
        const float u = accu[i][j][r];
        const float sl = g / (1.f + expf(-g));
        out[(size_t)row * Ipad + col] = (col < In) ? (bf16_t)(sl * u) : (bf16_t)0.f;
      }
    }
}

// ---------------------------------------------------------------- 64x128-tile GEMM (wo)
// m97-style: measured best for the N=1024/K=1024 shape at 2 blocks/CU.
__global__ __launch_bounds__(256) void k_gemm64(
    const bf16_t* __restrict__ A, const bf16_t* __restrict__ Bt,
    const float* __restrict__ bias, const float* __restrict__ resid,
    float* __restrict__ outf, int N, int K, int lda, int ldb, int nN) {
  __shared__ bf16_t As[64 * 64];
  __shared__ bf16_t Bs[128 * 64];
  int mblk, nblk;
  xcd_map(blockIdx.x, Mn / 64, nN, mblk, nblk);
  const int m0 = mblk * 64, n0 = nblk * 128;
  const int tid = threadIdx.x;
  const int lane = tid & 63, wid = tid >> 6;
  const int wc = wid * 32;
  const int l15 = lane & 15, quad = lane >> 4;
  const int sw = l15 & 7;
  const int srow_lo = lane >> 3, pchunk = lane & 7;

  f32x4 acc[4][2];
  const f32x4 z4 = {0.f, 0.f, 0.f, 0.f};
#pragma unroll
  for (int i = 0; i < 4; ++i)
#pragma unroll
    for (int j = 0; j < 2; ++j) acc[i][j] = z4;

  for (int k0 = 0; k0 < K; k0 += 64) {
#pragma unroll
    for (int c = 0; c < 2; ++c) {
      const int r = (wid * 2 + c) * 8 + srow_lo;
      const int gc = pchunk ^ (r & 7);
      cp16(A + (size_t)(m0 + r) * lda + k0 + gc * 8, As + (wid * 2 + c) * 512);
    }
#pragma unroll
    for (int c = 0; c < 4; ++c) {
      const int r = (wid * 4 + c) * 8 + srow_lo;
      const int gc = pchunk ^ (r & 7);
      cp16(Bt + (size_t)(n0 + r) * ldb + k0 + gc * 8, Bs + (wid * 4 + c) * 512);
    }
    __syncthreads();
#pragma unroll
    for (int kh = 0; kh < 2; ++kh) {
      const int ph = ((kh * 4 + quad) ^ sw) * 8;
      bf16x8 af[4], bfr[2];
#pragma unroll
      for (int i = 0; i < 4; ++i)
        af[i] = *(const bf16x8*)(As + (i * 16 + l15) * 64 + ph);
#pragma unroll
      for (int j = 0; j < 2; ++j)
        bfr[j] = *(const bf16x8*)(Bs + (wc + j * 16 + l15) * 64 + ph);
#pragma unroll
      for (int i = 0; i < 4; ++i)
#pragma unroll
        for (int j = 0; j < 2; ++j)
          acc[i][j] = __builtin_amdgcn_mfma_f32_16x16x32_bf16(af[i], bfr[j], acc[i][j], 0, 0, 0);
    }
    __syncthreads();
  }

#pragma unroll
  for (int i = 0; i < 4; ++i)
#pragma unroll
    for (int j = 0; j < 2; ++j) {
      const int col = n0 + wc + j * 16 + l15;
      const float bval = bias ? bias[col] : 0.f;
#pragma unroll
      for (int r = 0; r < 4; ++r) {
        const int row = m0 + i * 16 + quad * 4 + r;
        const size_t idx = (size_t)row * N + col;
        outf[idx] = acc[i][j][r] + bval + (resid ? resid[idx] : 0.f);
      }
    }
}

// ---------------------------------------------------------------- MFMA flash attention v3
__global__ __launch_bounds__(256) void k_attn(
    const bf16_t* __restrict__ qkv, bf16_t* __restrict__ Ob) {
  const int qt = (int)gridDim.x - 1 - (int)blockIdx.x;  // LPT
  const int h  = blockIdx.y;
  const int b  = blockIdx.z;
  constexpr int LDK = 72, LDP = 76;
  __shared__ bf16_t Ks[64 * LDK];      // [kseq][d]
  __shared__ bf16_t Vt[64 * LDK];      // [d][kseq]
  __shared__ bf16_t Ps[4][32 * LDP];   // per-wave P [qrow][kseq]

  const int tid  = threadIdx.x;
  const int lane = tid & 63, w = tid >> 6;
  const int l15  = lane & 15, quad = lane >> 4;

  constexpr float L2E = 1.4426950408889634f;
  const float slopeL = -exp2f(-0.5f * (float)(h + 1)) * L2E;

  bf16x8 aq[2][2];
#pragma unroll
  for (int g = 0; g < 2; ++g) {
    const int row = qt * 128 + w * 32 + g * 16 + l15;
    const bf16_t* qp = qkv + (size_t)(b * Sn + row) * 3072 + h * 64;
    aq[g][0] = *(const bf16x8*)(qp + quad * 8);
    aq[g][1] = *(const bf16x8*)(qp + 32 + quad * 8);
#pragma unroll
    for (int e = 0; e < 8; ++e) {
      aq[g][0][e] = (bf16_t)((float)aq[g][0][e] * 0.125f);
      aq[g][1][e] = (bf16_t)((float)aq[g][1][e] * 0.125f);
    }
  }

  int qrow[2];
  float rowterm[2][4];
#pragma unroll
  for (int g = 0; g < 2; ++g) {
    qrow[g] = qt * 128 + w * 32 + g * 16 + quad * 4;
#pragma unroll
    for (int rr = 0; rr < 4; ++rr) rowterm[g][rr] = slopeL * (float)(qrow[g] + rr);
  }
  float colbase[4];
#pragma unroll
  for (int t = 0; t < 4; ++t) colbase[t] = slopeL * (float)(t * 16 + l15);

  f32x4 o[2][4], lacc[2];
  const f32x4 z4 = {0.f, 0.f, 0.f, 0.f};
#pragma unroll
  for (int g = 0; g < 2; ++g) {
    lacc[g] = z4;
#pragma unroll
    for (int dt = 0; dt < 4; ++dt) o[g][dt] = z4;
  }
  bf16x8 ones;
#pragma unroll
  for (int e = 0; e < 8; ++e) ones[e] = (bf16_t)1.0f;

  const int r = tid >> 2, c0e = (tid & 3) * 16;
  const size_t kbase = (size_t)(b * Sn + r) * 3072 + 1024 + h * 64 + c0e;
  const size_t step  = (size_t)64 * 3072;

  s16x8 kr0 = *(const s16x8*)(qkv + kbase);
  s16x8 kr1 = *(const s16x8*)(qkv + kbase + 8);
  s16x8 vr0 = *(const s16x8*)(qkv + kbase + 1024);
  s16x8 vr1 = *(const s16x8*)(qkv + kbase + 1024 + 8);

  const int nkt = 2 * qt + 2;
  for (int kt = 0; kt < nkt; ++kt) {
    __syncthreads();
    *(s16x8*)(Ks + r * LDK + c0e)     = kr0;
    *(s16x8*)(Ks + r * LDK + c0e + 8) = kr1;
    {
      const bf16x8 v0 = *(const bf16x8*)&vr0, v1 = *(const bf16x8*)&vr1;
#pragma unroll
      for (int e = 0; e < 8; ++e) {
        Vt[(c0e + e) * LDK + r]     = v0[e];
        Vt[(c0e + 8 + e) * LDK + r] = v1[e];
      }
    }
    __syncthreads();
    if (kt + 1 < nkt) {
      const size_t kb = kbase + (size_t)(kt + 1) * step;
      kr0 = *(const s16x8*)(qkv + kb);
      kr1 = *(const s16x8*)(qkv + kb + 8);
      vr0 = *(const s16x8*)(qkv + kb + 1024);
      vr1 = *(const s16x8*)(qkv + kb + 1024 + 8);
    }

    const float kofs = slopeL * (float)(kt * 64);
    const bool diag = (kt + 2 >= nkt);

#pragma unroll
    for (int g = 0; g < 2; ++g) {
      f32x4 s[4];
#pragma unroll
      for (int t = 0; t < 4; ++t) s[t] = z4;
#pragma unroll
      for (int t = 0; t < 4; ++t) {
        bf16x8 bk0 = *(const bf16x8*)(Ks + (t * 16 + l15) * LDK + quad * 8);
        bf16x8 bk1 = *(const bf16x8*)(Ks + (t * 16 + l15) * LDK + 32 + quad * 8);
        s[t] = __builtin_amdgcn_mfma_f32_16x16x32_bf16(aq[g][0], bk0, s[t], 0, 0, 0);
        s[t] = __builtin_amdgcn_mfma_f32_16x16x32_bf16(aq[g][1], bk1, s[t], 0, 0, 0);
      }
#pragma unroll
      for (int t = 0; t < 4; ++t) {
        const int j = kt * 64 + t * 16 + l15;
#pragma unroll
        for (int rr = 0; rr < 4; ++rr) {
          float v2 = fmaf(s[t][rr], L2E, rowterm[g][rr] - (kofs + colbase[t]));
          if (diag && j > qrow[g] + rr) v2 = -3.0e38f;
          Ps[w][(g * 16 + quad * 4 + rr) * LDP + t * 16 + l15] = (bf16_t)exp2f(v2);
        }
      }
    }

#pragma unroll
    for (int g = 0; g < 2; ++g) {
#pragma unroll
      for (int kh = 0; kh < 2; ++kh) {
        bf16x8 pa = *(const bf16x8*)(Ps[w] + (g * 16 + l15) * LDP + kh * 32 + quad * 8);
        lacc[g] = __builtin_amdgcn_mfma_f32_16x16x32_bf16(pa, ones, lacc[g], 0, 0, 0);
#pragma unroll
        for (int dt = 0; dt < 4; ++dt) {
          bf16x8 bv = *(const bf16x8*)(Vt + (dt * 16 + l15) * LDK + kh * 32 + quad * 8);
          o[g][dt] = __builtin_amdgcn_mfma_f32_16x16x32_bf16(pa, bv, o[g][dt], 0, 0, 0);
        }
      }
    }
  }

#pragma unroll
  for (int g = 0; g < 2; ++g)
#pragma unroll
    for (int rr = 0; rr < 4; ++rr) {
      const float inv = 1.f / lacc[g][rr];
      bf16_t* op = Ob + (size_t)(b * Sn + qrow[g] + rr) * 1024 + h * 64;
#pragma unroll
      for (int dt = 0; dt < 4; ++dt)
        op[dt * 16 + l15] = (bf16_t)(o[g][dt][rr] * inv);
    }
}

// ---------------------------------------------------------------- launch
extern "C" void kernel_launch(void* const* d_in, const int* in_sizes, int n_in,
                              void* d_out, int out_size, void* d_ws, size_t ws_size,
                              hipStream_t stream) {
  (void)in_sizes; (void)n_in; (void)out_size; (void)ws_size;
  const float* x   = (const float*)d_in[0];
  const float* wq  = (const float*)d_in[1];
  const float* bq  = (const float*)d_in[2];
  const float* wk_ = (const float*)d_in[3];
  const float* bk  = (const float*)d_in[4];
  const float* wv  = (const float*)d_in[5];
  const float* bv  = (const float*)d_in[6];
  const float* wo  = (const float*)d_in[7];
  const float* bo  = (const float*)d_in[8];
  const float* wg  = (const float*)d_in[9];
  const float* wu  = (const float*)d_in[10];
  const float* wd  = (const float*)d_in[11];
  const float* ln1 = (const float*)d_in[12];
  const float* ln2 = (const float*)d_in[13];

  char* base = (char*)d_ws;
  const size_t MiB = 1024 * 1024;
  bf16_t* h1    = (bf16_t*)(base);              // 8 MiB
  bf16_t* wqkvT = (bf16_t*)(base + 8   * MiB);  // 6 MiB
  bf16_t* woT   = (bf16_t*)(base + 16  * MiB);  // 2 MiB
  bf16_t* wgT   = (bf16_t*)(base + 24  * MiB);  // 7.33 MiB
  bf16_t* wuT   = (bf16_t*)(base + 32  * MiB);  // 7.33 MiB
  bf16_t* wdT   = (bf16_t*)(base + 40  * MiB);  // 7.33 MiB
  bf16_t* qkvb  = (bf16_t*)(base + 48  * MiB);  // 24 MiB [M][3072]
  float*  res1  = (float*) (base + 72  * MiB);  // 16 MiB f32
  bf16_t* mlp   = (bf16_t*)(base + 88  * MiB);  // 30 MiB [M][3840]
  float*  parts = (float*) (base + 120 * MiB);  // 32 MiB: two f32 partials
  bf16_t* attnb = (bf16_t*)d_out;               // d_out as bf16 scratch
  bf16_t* h2    = (bf16_t*)d_out;

  const dim3 blk(256);

  // 1. all weight transposes in one packed launch
  TransJobs jobs;
  int start = 0;
  auto setjob = [&](int idx, const float* s, bf16_t* d, int R, int C) {
    const int bx = (C + 31) / 32, by = (R + 31) / 32;
    jobs.j[idx] = {s, d, R, C, bx, start};
    start += bx * by;
  };
  setjob(0, wq,  wqkvT,                       Dn, Dn);
  setjob(1, wk_, wqkvT + (size_t)Dn * Dn,     Dn, Dn);
  setjob(2, wv,  wqkvT + 2 * (size_t)Dn * Dn, Dn, Dn);
  setjob(3, wo,  woT, Dn, Dn);
  setjob(4, wg,  wgT, Dn, In);
  setjob(5, wu,  wuT, Dn, In);
  setjob(6, wd,  wdT, In, Dn);
  k_transpose_all<<<dim3(start), blk, 0, stream>>>(jobs);

  // 2. h1 = bf16(rmsnorm(x, ln1))
  k_rmsnorm<<<dim3(Mn), blk, 0, stream>>>(x, ln1, h1);

  // 3. qkvb = h1 @ wqkvT^T + bias  (128x128 pipelined, 768 blocks = 3/CU)
  k_gemm128b<<<dim3(Mn / 128, 3072 / 128), blk, 0, stream>>>(
      h1, wqkvT, bq, bk, bv, qkvb);

  // 4. flash attention (BM=128) -> attnb (d_out scratch)
  k_attn<<<dim3(Sn / 128, Hn, Bn), blk, 0, stream>>>(qkvb, attnb);

  // 5. res1 = attn @ wo^T + bo + x  (m97-style k_gemm64: measured best here)
  k_gemm64<<<dim3((Mn / 64) * (Dn / 128)), blk, 0, stream>>>(
      attnb, woT, bo, x, res1, Dn, Dn, Dn, Dn, Dn / 128);

  // 6. h2 = bf16(rmsnorm(res1, ln2))
  k_rmsnorm<<<dim3(Mn), blk, 0, stream>>>(res1, ln2, h2);

  // 7. mlp = silu(h2@wg)*(h2@wu) in ONE pipelined kernel, zero-padded cols
  k_gateup<<<dim3(Mn / 128, Ipad / 128), blk, 0, stream>>>(h2, wgT, wuT, mlp);

  // 8a. split-K down-proj partials (pipelined 128x128, 512 blocks = 2-3/CU)
  k_gemm128s<<<dim3(Mn / 128, Dn / 128, 2), blk, 0, stream>>>(
      mlp, wdT, parts, Ipad, In);

  // 8b. d_out = part0 + part1 + res1
  k_combine<<<dim3((Mn * Dn) / 1024), blk, 0, stream>>>(
      parts, parts + (size_t)Mn * Dn, res1, (float*)d_out);
}